// Round 5
// baseline (15834.607 us; speedup 1.0000x reference)
//
#include <hip/hip_runtime.h>
#include <hip/hip_bf16.h>

#define B_ 512
#define T_ 128
#define DIN_ 256
#define H_ 512
#define MROWS 32                 // batch rows per block
#define HBS 520                  // LDS h row stride (bf16 elems)
#define XW 4                     // x1 ring depth (steps)
#define OUT_MAIN ((size_t)B_ * T_ * H_)

typedef __attribute__((ext_vector_type(8))) short short8;
typedef __attribute__((ext_vector_type(4))) float f32x4;

__device__ __forceinline__ float sigm(float v) { return 1.0f / (1.0f + __expf(-v)); }

__device__ __forceinline__ unsigned short f2bf(float f) {
    union { __hip_bfloat16 b; unsigned short u; } c;
    c.b = __float2bfloat16(f);
    return c.u;
}

__device__ __forceinline__ short8 cvt8v(f32x4 u, f32x4 v) {
    short8 o;
    o[0] = (short)f2bf(u[0]); o[1] = (short)f2bf(u[1]);
    o[2] = (short)f2bf(u[2]); o[3] = (short)f2bf(u[3]);
    o[4] = (short)f2bf(v[0]); o[5] = (short)f2bf(v[1]);
    o[6] = (short)f2bf(v[2]); o[7] = (short)f2bf(v[3]);
    return o;
}

// 16B cross-XCD coherent load (2 x 8B relaxed agent atomics -> sc0 sc1).
__device__ __forceinline__ short8 load_sc16(const __hip_bfloat16* p) {
    union { unsigned long long u[2]; short8 v; } r;
    r.u[0] = __hip_atomic_load((const unsigned long long*)p,       __ATOMIC_RELAXED, __HIP_MEMORY_SCOPE_AGENT);
    r.u[1] = __hip_atomic_load((const unsigned long long*)(p + 4), __ATOMIC_RELAXED, __HIP_MEMORY_SCOPE_AGENT);
    return r.v;
}

__device__ __forceinline__ void store_sc8(__hip_bfloat16* p, f32x4 h4) {
    union { unsigned short s[4]; unsigned long long u; } r;
    r.s[0] = f2bf(h4[0]); r.s[1] = f2bf(h4[1]);
    r.s[2] = f2bf(h4[2]); r.s[3] = f2bf(h4[3]);
    __hip_atomic_store((unsigned long long*)p, r.u, __ATOMIC_RELAXED, __HIP_MEMORY_SCOPE_AGENT);
}

__global__ void prep_kernel(const float* __restrict__ wih0, const float* __restrict__ whh0,
                            const float* __restrict__ wih1, const float* __restrict__ whh1,
                            __hip_bfloat16* __restrict__ bw, int* __restrict__ flags)
{
    int tid = blockIdx.x * blockDim.x + threadIdx.x;
    int stride = gridDim.x * blockDim.x;
    if (tid < 32) flags[tid] = 0;
    const int N0 = 1536 * DIN_, N1 = 1536 * H_;
    __hip_bfloat16* b0 = bw;
    __hip_bfloat16* b1 = b0 + N0;
    __hip_bfloat16* b2 = b1 + N1;
    __hip_bfloat16* b3 = b2 + N1;
    for (int i = tid; i < N0; i += stride) b0[i] = __float2bfloat16(wih0[i]);
    for (int i = tid; i < N1; i += stride) b1[i] = __float2bfloat16(whh0[i]);
    for (int i = tid; i < N1; i += stride) b2[i] = __float2bfloat16(wih1[i]);
    for (int i = tid; i < N1; i += stride) b3[i] = __float2bfloat16(whh1[i]);
}

#define MM(wf, af, acc) acc = __builtin_amdgcn_mfma_f32_16x16x32_bf16(wf, af, acc, 0, 0, 0)

// One K-chunk (32) of the 3-gate, 64-j (4 jt), 2-m GEMM group. T2 = aIN (gi) or aHN (gh).
#define TRIP(WB, WK, KC, A0, A1, T2) { \
    _Pragma("unroll") for (int jt = 0; jt < 4; ++jt) { \
        const short8 wf = *(const short8*)((WB) + (size_t)(jb + jt * 16 + l15) * (WK) + (KC) * 32 + kg); \
        MM(wf, A0, aR[jt][0]); MM(wf, A1, aR[jt][1]); } \
    _Pragma("unroll") for (int jt = 0; jt < 4; ++jt) { \
        const short8 wf = *(const short8*)((WB) + (size_t)(H_ + jb + jt * 16 + l15) * (WK) + (KC) * 32 + kg); \
        MM(wf, A0, aZ[jt][0]); MM(wf, A1, aZ[jt][1]); } \
    _Pragma("unroll") for (int jt = 0; jt < 4; ++jt) { \
        const short8 wf = *(const short8*)((WB) + (size_t)(2 * H_ + jb + jt * 16 + l15) * (WK) + (KC) * 32 + kg); \
        MM(wf, A0, T2[jt][0]); MM(wf, A1, T2[jt][1]); } }

// 32 blocks = 2 layers x 16 batch tiles (M=32). 512 threads = 8 waves; wave w owns
// j-slice [w*64, w*64+64) of all 3 gates. Weights streamed from ws (bf16). No barriers
// across blocks; l0 -> l1 handoff via x1 ring + monotonic flags.
__global__ __launch_bounds__(512) void gru_bt(
    const float* __restrict__ x, const int* __restrict__ is_init,
    const float* __restrict__ h_in,
    const float* __restrict__ bih0, const float* __restrict__ bhh0,
    const float* __restrict__ bih1, const float* __restrict__ bhh1,
    const __hip_bfloat16* __restrict__ bw,
    __hip_bfloat16* __restrict__ x1, int* __restrict__ flags,
    float* __restrict__ out)
{
    __shared__ __hip_bfloat16 hb[MROWS * HBS];   // 33280 B: h state bf16 (A-operand for gh)
    __shared__ float blds[4 * H_];               //  8192 B: biases

    const int bid = blockIdx.x;
    const int l  = bid >> 4;
    const int bt = bid & 15;
    const int rb = bt * MROWS;
    const int tid = threadIdx.x;
    const int lane = tid & 63;
    const int w = tid >> 6;
    const int l15 = lane & 15;
    const int kg  = (lane >> 4) * 8;   // k offset within a 32-chunk
    const int qr4 = (lane >> 4) * 4;   // j-quad within 16
    const int jb  = w * 64;

    const __hip_bfloat16* Wi = l ? (bw + 1536 * DIN_ + 1536 * H_) : bw;
    const __hip_bfloat16* Wh = l ? (bw + 1536 * DIN_ + 2 * 1536 * H_) : (bw + 1536 * DIN_);
    const float* bi = l ? bih1 : bih0;
    const float* bh = l ? bhh1 : bhh0;

    for (int i = tid; i < H_; i += 512) {
        blds[i]            = bi[i] + bh[i];
        blds[H_ + i]       = bi[H_ + i] + bh[H_ + i];
        blds[2 * H_ + i]   = bi[2 * H_ + i];
        blds[3 * H_ + i]   = bh[2 * H_ + i];
    }

    // initial h: f32 master in regs (lane: rows m*16+l15, cols jb+jt*16+qr4..+3)
    f32x4 hp[4][2];
    #pragma unroll
    for (int jt = 0; jt < 4; ++jt)
        #pragma unroll
        for (int m = 0; m < 2; ++m) {
            hp[jt][m] = *(const f32x4*)&h_in[((size_t)(rb + m * 16 + l15) * 2 + l) * H_ + jb + jt * 16 + qr4];
            union { unsigned short s[4]; unsigned long long u; } pk;
            pk.s[0] = f2bf(hp[jt][m][0]); pk.s[1] = f2bf(hp[jt][m][1]);
            pk.s[2] = f2bf(hp[jt][m][2]); pk.s[3] = f2bf(hp[jt][m][3]);
            *(unsigned long long*)&hb[(m * 16 + l15) * HBS + jb + jt * 16 + qr4] = pk.u;
        }
    __syncthreads();

    const short8 zed = {0, 0, 0, 0, 0, 0, 0, 0};

    for (int s = 0; s < T_; ++s) {
        f32x4 aR[4][2], aZ[4][2], aIN[4][2], aHN[4][2];
        #pragma unroll
        for (int jt = 0; jt < 4; ++jt)
            #pragma unroll
            for (int m = 0; m < 2; ++m) {
                aR[jt][m] = f32x4{0.f, 0.f, 0.f, 0.f};
                aZ[jt][m] = f32x4{0.f, 0.f, 0.f, 0.f};
                aIN[jt][m] = f32x4{0.f, 0.f, 0.f, 0.f};
                aHN[jt][m] = f32x4{0.f, 0.f, 0.f, 0.f};
            }

        const bool z0 = is_init[(rb + l15) * T_ + s] != 0;
        const bool z1 = is_init[(rb + 16 + l15) * T_ + s] != 0;

        if (l == 0) {
            // ---- gi over x (f32, no dependency) ----
            const float* xr0 = x + ((size_t)(rb + l15) * T_ + s) * DIN_;
            const float* xr1 = x + ((size_t)(rb + 16 + l15) * T_ + s) * DIN_;
            #pragma unroll 2
            for (int kc = 0; kc < DIN_ / 32; ++kc) {
                short8 a0 = cvt8v(*(const f32x4*)(xr0 + kc * 32 + kg), *(const f32x4*)(xr0 + kc * 32 + kg + 4));
                short8 a1 = cvt8v(*(const f32x4*)(xr1 + kc * 32 + kg), *(const f32x4*)(xr1 + kc * 32 + kg + 4));
                TRIP(Wi, DIN_, kc, a0, a1, aIN);
            }
            // ---- gh over hb ----
            #pragma unroll 2
            for (int kc = 0; kc < H_ / 32; ++kc) {
                short8 a0 = *(const short8*)&hb[l15 * HBS + kc * 32 + kg];
                short8 a1 = *(const short8*)&hb[(16 + l15) * HBS + kc * 32 + kg];
                if (z0) a0 = zed;
                if (z1) a1 = zed;
                TRIP(Wh, H_, kc, a0, a1, aHN);
            }
            // ring backpressure: l1 must have consumed slot (s - XW)
            if (s >= XW && lane == 0) {
                while (__hip_atomic_load(&flags[16 + bt], __ATOMIC_RELAXED, __HIP_MEMORY_SCOPE_AGENT) < s - XW + 1)
                    __builtin_amdgcn_s_sleep(1);
            }
        } else {
            // ---- gh over hb (recurrent, before the flag wait) ----
            #pragma unroll 2
            for (int kc = 0; kc < H_ / 32; ++kc) {
                short8 a0 = *(const short8*)&hb[l15 * HBS + kc * 32 + kg];
                short8 a1 = *(const short8*)&hb[(16 + l15) * HBS + kc * 32 + kg];
                if (z0) a0 = zed;
                if (z1) a1 = zed;
                TRIP(Wh, H_, kc, a0, a1, aHN);
            }
            // ---- wait for x1[s], then gi over it ----
            if (lane == 0) {
                while (__hip_atomic_load(&flags[bt], __ATOMIC_RELAXED, __HIP_MEMORY_SCOPE_AGENT) < s + 1)
                    __builtin_amdgcn_s_sleep(1);
            }
            const __hip_bfloat16* p0 = x1 + ((size_t)(s & (XW - 1)) * B_ + rb + l15) * H_;
            const __hip_bfloat16* p1 = p0 + (size_t)16 * H_;
            #pragma unroll 2
            for (int kc = 0; kc < H_ / 32; ++kc) {
                short8 a0 = load_sc16(p0 + kc * 32 + kg);
                short8 a1 = load_sc16(p1 + kc * 32 + kg);
                TRIP(Wi, H_, kc, a0, a1, aIN);
            }
        }

        __syncthreads();   // all hb reads done before epilogue overwrites state

        __hip_bfloat16* x1s = x1 + (size_t)(s & (XW - 1)) * B_ * H_;
        #pragma unroll
        for (int jt = 0; jt < 4; ++jt) {
            const int j4 = jb + jt * 16 + qr4;
            const f32x4 bR  = *(const f32x4*)&blds[j4];
            const f32x4 bZ  = *(const f32x4*)&blds[H_ + j4];
            const f32x4 bIN = *(const f32x4*)&blds[2 * H_ + j4];
            const f32x4 bHN = *(const f32x4*)&blds[3 * H_ + j4];
            #pragma unroll
            for (int m = 0; m < 2; ++m) {
                const int b = rb + m * 16 + l15;
                const bool ini = m ? z1 : z0;
                f32x4 hv;
                #pragma unroll
                for (int r = 0; r < 4; ++r) {
                    const float rr = sigm(aR[jt][m][r] + bR[r]);
                    const float zz = sigm(aZ[jt][m][r] + bZ[r]);
                    const float nn = tanhf(aIN[jt][m][r] + bIN[r] + rr * (aHN[jt][m][r] + bHN[r]));
                    const float hprev = ini ? 0.0f : hp[jt][m][r];
                    hv[r] = (1.0f - zz) * nn + zz * hprev;
                }
                hp[jt][m] = hv;
                union { unsigned short us[4]; unsigned long long u; } pk;
                pk.us[0] = f2bf(hv[0]); pk.us[1] = f2bf(hv[1]);
                pk.us[2] = f2bf(hv[2]); pk.us[3] = f2bf(hv[3]);
                *(unsigned long long*)&hb[(m * 16 + l15) * HBS + j4] = pk.u;
                if (l) {
                    *(f32x4*)&out[((size_t)b * T_ + s) * H_ + j4] = hv;
                    if (s == T_ - 1)
                        *(f32x4*)&out[OUT_MAIN + ((size_t)b * 2 + 1) * H_ + j4] = hv;
                } else {
                    store_sc8(x1s + (size_t)b * H_ + j4, hv);
                    if (s == T_ - 1)
                        *(f32x4*)&out[OUT_MAIN + ((size_t)b * 2 + 0) * H_ + j4] = hv;
                }
            }
        }

        __syncthreads();   // hb writes + x1 sc-stores drained (vmcnt0) in all waves
        if (tid == 0) {
            int* fl = l ? &flags[16 + bt] : &flags[bt];
            __hip_atomic_store(fl, s + 1, __ATOMIC_RELAXED, __HIP_MEMORY_SCOPE_AGENT);
        }
    }
}

extern "C" void kernel_launch(void* const* d_in, const int* in_sizes, int n_in,
                              void* d_out, int out_size, void* d_ws, size_t ws_size,
                              hipStream_t stream) {
    (void)in_sizes; (void)n_in; (void)out_size; (void)ws_size;
    const float* x    = (const float*)d_in[0];
    const int*   isin = (const int*)d_in[1];
    const float* h_in = (const float*)d_in[2];
    const float* wih0 = (const float*)d_in[3];
    const float* whh0 = (const float*)d_in[4];
    const float* bih0 = (const float*)d_in[5];
    const float* bhh0 = (const float*)d_in[6];
    const float* wih1 = (const float*)d_in[7];
    const float* whh1 = (const float*)d_in[8];
    const float* bih1 = (const float*)d_in[9];
    const float* bhh1 = (const float*)d_in[10];
    float* out = (float*)d_out;

    char* wsb = (char*)d_ws;
    __hip_bfloat16* bw = (__hip_bfloat16*)wsb;             // 2,752,512 bf16 = 5,505,024 B
    int* flags = (int*)(wsb + 5505024);                    // 32 ints (+pad to 128 B)
    __hip_bfloat16* x1 = (__hip_bfloat16*)(wsb + 5505152); // XW x [B_ x H_] bf16 = 4 MiB

    prep_kernel<<<dim3(1024), dim3(256), 0, stream>>>(wih0, whh0, wih1, whh1, bw, flags);

    gru_bt<<<dim3(32), dim3(512), 0, stream>>>(
        x, isin, h_in, bih0, bhh0, bih1, bhh1, bw, x1, flags, out);
}

// Round 6
// 2097.933 us; speedup vs baseline: 7.5477x; 7.5477x over previous
//
#include <hip/hip_runtime.h>
#include <hip/hip_bf16.h>

#define B_ 512
#define T_ 128
#define DIN_ 256
#define H_ 512
#define KPAD 1048          // LDS weight row stride (bf16): 524 dwords -> 2-way max conflict
#define WROWS 48           // 3 gates x 16 j
#define CPAD 52            // combine buffer row stride (f32)
#define HS ((size_t)B_ * H_)
#define OUT_MAIN ((size_t)B_ * T_ * H_)

typedef __attribute__((ext_vector_type(8))) short short8;
typedef __attribute__((ext_vector_type(4))) float f32x4;

__device__ __forceinline__ float sigm(float v) { return 1.0f / (1.0f + __expf(-v)); }

__device__ __forceinline__ unsigned short f2bf(float f) {
    union { __hip_bfloat16 b; unsigned short u; } c;
    c.b = __float2bfloat16(f);
    return c.u;
}

__device__ __forceinline__ short8 cvt8v(f32x4 u, f32x4 v) {
    short8 o;
    o[0] = (short)f2bf(u[0]); o[1] = (short)f2bf(u[1]);
    o[2] = (short)f2bf(u[2]); o[3] = (short)f2bf(u[3]);
    o[4] = (short)f2bf(v[0]); o[5] = (short)f2bf(v[1]);
    o[6] = (short)f2bf(v[2]); o[7] = (short)f2bf(v[3]);
    return o;
}

// 16B of h-state via two 8B agent-scope atomic loads (coherent point, no fences).
__device__ __forceinline__ short8 load_h16(const __hip_bfloat16* p) {
    union { unsigned long long u[2]; short8 v; } r;
    r.u[0] = __hip_atomic_load((const unsigned long long*)p,       __ATOMIC_RELAXED, __HIP_MEMORY_SCOPE_AGENT);
    r.u[1] = __hip_atomic_load((const unsigned long long*)(p + 4), __ATOMIC_RELAXED, __HIP_MEMORY_SCOPE_AGENT);
    return r.v;
}

__device__ __forceinline__ void store_h8(__hip_bfloat16* p, const float* h4) {
    union { unsigned short s[4]; unsigned long long u; } r;
    r.s[0] = f2bf(h4[0]); r.s[1] = f2bf(h4[1]);
    r.s[2] = f2bf(h4[2]); r.s[3] = f2bf(h4[3]);
    __hip_atomic_store((unsigned long long*)p, r.u, __ATOMIC_RELAXED, __HIP_MEMORY_SCOPE_AGENT);
}

__global__ void init_kernel(const float* __restrict__ h_in,
                            __hip_bfloat16* __restrict__ h0b,
                            __hip_bfloat16* __restrict__ h1b,
                            int* __restrict__ flags)
{
    int i = blockIdx.x * blockDim.x + threadIdx.x;
    if (i < 512) flags[i] = 0;
    if (i < (int)(B_ * H_)) {
        int b = i >> 9, j = i & (H_ - 1);
        h0b[HS + i] = __float2bfloat16(h_in[((size_t)b * 2 + 0) * H_ + j]);
        h1b[HS + i] = __float2bfloat16(h_in[((size_t)b * 2 + 1) * H_ + j]);
    }
}

// Persistent kernel. 256 blocks x 512 threads, 1 block/CU (LDS-forced).
// block -> (layer l, batch-tile bt of 128 rows, j-tile jt of 16 cols)
// waves: mq in 0..3 (32 batch rows) x part (0 = input-side GEMM, 1 = hidden-side GEMM)
// MFMA operands SWAPPED: D[j][b] = mfma(W_frag, h_frag) -> lane holds 4 consecutive j.
// Phase sync: per-block monotonic flags (sc-store publish) + 64-lane parallel poll.
__global__ __launch_bounds__(512) void gru_persist(
    const float* __restrict__ x, const int* __restrict__ is_init,
    const float* __restrict__ h_in,
    const float* __restrict__ wih0, const float* __restrict__ whh0,
    const float* __restrict__ bih0, const float* __restrict__ bhh0,
    const float* __restrict__ wih1, const float* __restrict__ whh1,
    const float* __restrict__ bih1, const float* __restrict__ bhh1,
    __hip_bfloat16* __restrict__ h0b, __hip_bfloat16* __restrict__ h1b,
    int* __restrict__ flags, float* __restrict__ out)
{
    __shared__ __hip_bfloat16 wlds[WROWS * KPAD];   // 100608 B
    __shared__ float cmb[128 * CPAD];               //  26624 B

    const int bid = blockIdx.x;
    const int l   = bid >> 7;
    const int bt  = (bid >> 5) & 3;
    const int jt  = bid & 31;
    const int tid = threadIdx.x;
    const int lane = tid & 63;
    const int wid  = tid >> 6;
    const int mq   = wid >> 1;
    const int part = wid & 1;
    const int l15  = lane & 15;
    const int kg   = (lane >> 4) * 8;   // k offset within a 32-chunk
    const int qr4  = (lane >> 4) * 4;   // j-quad base within 16
    const int rb   = bt * 128 + mq * 32;
    const int j4   = jt * 16 + qr4;

    const float* Wi = l ? wih1 : wih0;
    const float* Wh = l ? whh1 : whh0;
    const float* bi = l ? bih1 : bih0;
    const float* bh = l ? bhh1 : bhh0;
    const int KI = l ? H_ : DIN_;

    // ---- stage weight slice to LDS (f32 -> bf16), once ----
    {
        const int nci = KI / 8;
        for (int idx = tid; idx < WROWS * nci; idx += 512) {
            int r = idx / nci, c8 = idx - r * nci;
            int grow = (r >> 4) * H_ + jt * 16 + (r & 15);
            const float* p = Wi + (size_t)grow * KI + c8 * 8;
            *(short8*)&wlds[r * KPAD + c8 * 8] = cvt8v(*(const f32x4*)p, *(const f32x4*)(p + 4));
        }
        for (int idx = tid; idx < WROWS * 64; idx += 512) {
            int r = idx >> 6, c8 = idx & 63;
            int grow = (r >> 4) * H_ + jt * 16 + (r & 15);
            const float* p = Wh + (size_t)grow * H_ + c8 * 8;
            *(short8*)&wlds[r * KPAD + KI + c8 * 8] = cvt8v(*(const f32x4*)p, *(const f32x4*)(p + 4));
        }
    }

    // ---- hoisted per-lane constants ----
    const f32x4 b_r  = *(const f32x4*)&bi[j4]          + *(const f32x4*)&bh[j4];
    const f32x4 b_z  = *(const f32x4*)&bi[H_ + j4]     + *(const f32x4*)&bh[H_ + j4];
    const f32x4 b_in = *(const f32x4*)&bi[2 * H_ + j4];
    const f32x4 b_hn = *(const f32x4*)&bh[2 * H_ + j4];

    f32x4 hp[2];   // f32 master state: rows rb + mm*16 + l15, cols j4..j4+3
    #pragma unroll
    for (int mm = 0; mm < 2; ++mm)
        hp[mm] = *(const f32x4*)&h_in[((size_t)(rb + mm * 16 + l15) * 2 + l) * H_ + j4];

    __syncthreads();

    const short8 zed = {0, 0, 0, 0, 0, 0, 0, 0};

    for (int t = 0; t <= T_; ++t) {
        if (l == 0 && t == T_) break;         // l0 has no work in the last slot
        const int s = l ? (t - 1) : t;
        const bool active = (s >= 0);

        // ---- phase-start wait: all 64 group blocks (both layers, this bt) done t-1 ----
        if (t > 0 && wid == 0) {
            const int fidx = ((lane >> 5) << 7) + bt * 32 + (lane & 31);
            while (__hip_atomic_load(&flags[fidx], __ATOMIC_RELAXED, __HIP_MEMORY_SCOPE_AGENT) < t)
                __builtin_amdgcn_s_sleep(2);
        }
        __syncthreads();

        f32x4 acc[2][3];
        #pragma unroll
        for (int mm = 0; mm < 2; ++mm)
            #pragma unroll
            for (int g = 0; g < 3; ++g)
                acc[mm][g] = f32x4{0.f, 0.f, 0.f, 0.f};

        if (active) {
            if (part == 0) {
                // ---- input-side GEMM (gi) ----
                if (l == 0) {
                    const float* xr0 = x + ((size_t)(rb + l15) * T_ + s) * DIN_ + kg;
                    const float* xr1 = x + ((size_t)(rb + 16 + l15) * T_ + s) * DIN_ + kg;
                    #pragma unroll
                    for (int k0 = 0; k0 < DIN_; k0 += 32) {
                        short8 a0 = cvt8v(*(const f32x4*)(xr0 + k0), *(const f32x4*)(xr0 + k0 + 4));
                        short8 a1 = cvt8v(*(const f32x4*)(xr1 + k0), *(const f32x4*)(xr1 + k0 + 4));
                        #pragma unroll
                        for (int g = 0; g < 3; ++g) {
                            short8 wf = *(const short8*)&wlds[(g * 16 + l15) * KPAD + k0 + kg];
                            acc[0][g] = __builtin_amdgcn_mfma_f32_16x16x32_bf16(wf, a0, acc[0][g], 0, 0, 0);
                            acc[1][g] = __builtin_amdgcn_mfma_f32_16x16x32_bf16(wf, a1, acc[1][g], 0, 0, 0);
                        }
                    }
                } else {
                    const __hip_bfloat16* hs = h0b + (size_t)(s & 1) * HS;
                    const __hip_bfloat16* r0 = hs + (size_t)(rb + l15) * H_ + kg;
                    const __hip_bfloat16* r1 = hs + (size_t)(rb + 16 + l15) * H_ + kg;
                    #pragma unroll
                    for (int k0 = 0; k0 < H_; k0 += 32) {
                        short8 a0 = load_h16(r0 + k0);
                        short8 a1 = load_h16(r1 + k0);
                        #pragma unroll
                        for (int g = 0; g < 3; ++g) {
                            short8 wf = *(const short8*)&wlds[(g * 16 + l15) * KPAD + k0 + kg];
                            acc[0][g] = __builtin_amdgcn_mfma_f32_16x16x32_bf16(wf, a0, acc[0][g], 0, 0, 0);
                            acc[1][g] = __builtin_amdgcn_mfma_f32_16x16x32_bf16(wf, a1, acc[1][g], 0, 0, 0);
                        }
                    }
                }
                // dump gi to combine buffer: row = b-local, col = g*16 + j-quad
                #pragma unroll
                for (int mm = 0; mm < 2; ++mm)
                    #pragma unroll
                    for (int g = 0; g < 3; ++g)
                        *(f32x4*)&cmb[(mq * 32 + mm * 16 + l15) * CPAD + g * 16 + qr4] = acc[mm][g];
            } else {
                // ---- hidden-side GEMM (gh), per-row is_init zeroing ----
                const __hip_bfloat16* hs = (l ? h1b : h0b) + (size_t)((s + 1) & 1) * HS;
                const bool z0 = is_init[(rb + l15) * T_ + s] != 0;
                const bool z1 = is_init[(rb + 16 + l15) * T_ + s] != 0;
                const __hip_bfloat16* r0 = hs + (size_t)(rb + l15) * H_ + kg;
                const __hip_bfloat16* r1 = hs + (size_t)(rb + 16 + l15) * H_ + kg;
                #pragma unroll
                for (int k0 = 0; k0 < H_; k0 += 32) {
                    short8 a0 = z0 ? zed : load_h16(r0 + k0);
                    short8 a1 = z1 ? zed : load_h16(r1 + k0);
                    #pragma unroll
                    for (int g = 0; g < 3; ++g) {
                        short8 wf = *(const short8*)&wlds[(g * 16 + l15) * KPAD + KI + k0 + kg];
                        acc[0][g] = __builtin_amdgcn_mfma_f32_16x16x32_bf16(wf, a0, acc[0][g], 0, 0, 0);
                        acc[1][g] = __builtin_amdgcn_mfma_f32_16x16x32_bf16(wf, a1, acc[1][g], 0, 0, 0);
                    }
                }
            }
        }

        __syncthreads();   // gi combine visible to gh waves

        if (active && part == 1) {
            __hip_bfloat16* Hout = (l ? h1b : h0b) + (size_t)(s & 1) * HS;
            #pragma unroll
            for (int mm = 0; mm < 2; ++mm) {
                const int b = rb + mm * 16 + l15;
                const bool ini = is_init[b * T_ + s] != 0;
                const float* cp = &cmb[(mq * 32 + mm * 16 + l15) * CPAD + qr4];
                const f32x4 gi_r = *(const f32x4*)(cp);
                const f32x4 gi_z = *(const f32x4*)(cp + 16);
                const f32x4 gi_n = *(const f32x4*)(cp + 32);
                float hv[4];
                #pragma unroll
                for (int r = 0; r < 4; ++r) {
                    const float rr = sigm(gi_r[r] + acc[mm][0][r] + b_r[r]);
                    const float zz = sigm(gi_z[r] + acc[mm][1][r] + b_z[r]);
                    const float nn = tanhf(gi_n[r] + b_in[r] + rr * (acc[mm][2][r] + b_hn[r]));
                    const float hprev = ini ? 0.0f : hp[mm][r];
                    hv[r] = (1.0f - zz) * nn + zz * hprev;
                    hp[mm][r] = hv[r];
                }
                store_h8(&Hout[(size_t)b * H_ + j4], hv);
                if (l) {
                    *(f32x4*)&out[((size_t)b * T_ + s) * H_ + j4] = f32x4{hv[0], hv[1], hv[2], hv[3]};
                    if (s == T_ - 1)
                        *(f32x4*)&out[OUT_MAIN + ((size_t)b * 2 + 1) * H_ + j4] = f32x4{hv[0], hv[1], hv[2], hv[3]};
                } else if (s == T_ - 1) {
                    *(f32x4*)&out[OUT_MAIN + ((size_t)b * 2 + 0) * H_ + j4] = f32x4{hv[0], hv[1], hv[2], hv[3]};
                }
            }
        }

        __syncthreads();   // all sc-stores drained (vmcnt0 per wave) before publish
        if (tid == 0)
            __hip_atomic_store(&flags[bid], t + 1, __ATOMIC_RELAXED, __HIP_MEMORY_SCOPE_AGENT);
    }
}

extern "C" void kernel_launch(void* const* d_in, const int* in_sizes, int n_in,
                              void* d_out, int out_size, void* d_ws, size_t ws_size,
                              hipStream_t stream) {
    (void)in_sizes; (void)n_in; (void)out_size; (void)ws_size;
    const float* x    = (const float*)d_in[0];
    const int*   isin = (const int*)d_in[1];
    const float* h_in = (const float*)d_in[2];
    const float* wih0 = (const float*)d_in[3];
    const float* whh0 = (const float*)d_in[4];
    const float* bih0 = (const float*)d_in[5];
    const float* bhh0 = (const float*)d_in[6];
    const float* wih1 = (const float*)d_in[7];
    const float* whh1 = (const float*)d_in[8];
    const float* bih1 = (const float*)d_in[9];
    const float* bhh1 = (const float*)d_in[10];
    float* out = (float*)d_out;

    char* wsb = (char*)d_ws;
    __hip_bfloat16* h0b = (__hip_bfloat16*)wsb;            // 2 x [512*512] ping-pong
    __hip_bfloat16* h1b = h0b + 2 * HS;
    int* flags = (int*)(wsb + 4 * HS * 2);                 // 256 per-block phase flags

    init_kernel<<<dim3(1024), dim3(256), 0, stream>>>(h_in, h0b, h1b, flags);

    gru_persist<<<dim3(256), dim3(512), 0, stream>>>(
        x, isin, h_in,
        wih0, whh0, bih0, bhh0,
        wih1, whh1, bih1, bhh1,
        h0b, h1b, flags, out);
}

// Round 7
// 1488.901 us; speedup vs baseline: 10.6351x; 1.4090x over previous
//
#include <hip/hip_runtime.h>
#include <hip/hip_bf16.h>

#define B_ 512
#define T_ 128
#define DIN_ 256
#define H_ 512
#define KP_ 520             // LDS weight row stride (bf16) for K=512 stages
#define KP0_ 264            // for K=256 stage (P0)
#define HS ((size_t)B_ * H_)
#define OUT_MAIN ((size_t)B_ * T_ * H_)

// ws byte offsets
#define OFF_H1  2097152ull
#define OFF_GI0 4194304ull
#define OFF_GI1 10485760ull
#define OFF_FLG 16777216ull

typedef __attribute__((ext_vector_type(8))) short short8;
typedef __attribute__((ext_vector_type(4))) float f32x4;

__device__ __forceinline__ float sigm(float v) { return 1.0f / (1.0f + __expf(-v)); }

__device__ __forceinline__ unsigned short f2bf(float f) {
    union { __hip_bfloat16 b; unsigned short u; } c;
    c.b = __float2bfloat16(f);
    return c.u;
}

__device__ __forceinline__ short8 cvt8v(f32x4 u, f32x4 v) {
    short8 o;
    o[0] = (short)f2bf(u[0]); o[1] = (short)f2bf(u[1]);
    o[2] = (short)f2bf(u[2]); o[3] = (short)f2bf(u[3]);
    o[4] = (short)f2bf(v[0]); o[5] = (short)f2bf(v[1]);
    o[6] = (short)f2bf(v[2]); o[7] = (short)f2bf(v[3]);
    return o;
}

// coherent-point accesses (sc0 sc1): cross-XCD safe, no fences needed
__device__ __forceinline__ short8 load_h16(const __hip_bfloat16* p) {
    union { unsigned long long u[2]; short8 v; } r;
    r.u[0] = __hip_atomic_load((const unsigned long long*)p,       __ATOMIC_RELAXED, __HIP_MEMORY_SCOPE_AGENT);
    r.u[1] = __hip_atomic_load((const unsigned long long*)(p + 4), __ATOMIC_RELAXED, __HIP_MEMORY_SCOPE_AGENT);
    return r.v;
}

__device__ __forceinline__ unsigned long long load_sc8(const __hip_bfloat16* p) {
    return __hip_atomic_load((const unsigned long long*)p, __ATOMIC_RELAXED, __HIP_MEMORY_SCOPE_AGENT);
}

__device__ __forceinline__ void store_h8(__hip_bfloat16* p, f32x4 h4) {
    union { unsigned short s[4]; unsigned long long u; } r;
    r.s[0] = f2bf(h4[0]); r.s[1] = f2bf(h4[1]);
    r.s[2] = f2bf(h4[2]); r.s[3] = f2bf(h4[3]);
    __hip_atomic_store((unsigned long long*)p, r.u, __ATOMIC_RELAXED, __HIP_MEMORY_SCOPE_AGENT);
}

__device__ __forceinline__ f32x4 unpk(unsigned long long u) {
    f32x4 r;
    r[0] = __uint_as_float((unsigned)(u & 0xffffull) << 16);
    r[1] = __uint_as_float((unsigned)((u >> 16) & 0xffffull) << 16);
    r[2] = __uint_as_float((unsigned)((u >> 32) & 0xffffull) << 16);
    r[3] = __uint_as_float((unsigned)((u >> 48) & 0xffffull) << 16);
    return r;
}

__global__ void init_kernel(int* __restrict__ flg)
{
    int i = blockIdx.x * blockDim.x + threadIdx.x;
    if (i < 32768) flg[i] = 0;
}

// 6-fragment MFMA over one K-chunk set. acc[jf], jf = g*2 + jh.
template<int NKC, int KP>
__device__ __forceinline__ void gemm_bf(const __hip_bfloat16* __restrict__ hr,
                                        const __hip_bfloat16* wl,
                                        int l15, int kg, bool z, f32x4* acc)
{
    const short8 zed = {0,0,0,0,0,0,0,0};
    #pragma unroll
    for (int kc = 0; kc < NKC; ++kc) {
        short8 bf = z ? zed : load_h16(hr + kc * 32 + kg);
        #pragma unroll
        for (int g = 0; g < 3; ++g)
            #pragma unroll
            for (int jh = 0; jh < 2; ++jh) {
                short8 wf = *(const short8*)&wl[(g * 32 + jh * 16 + l15) * KP + kc * 32 + kg];
                acc[g * 2 + jh] = __builtin_amdgcn_mfma_f32_16x16x32_bf16(wf, bf, acc[g * 2 + jh], 0, 0, 0);
            }
    }
}

template<int NKC, int KP>
__device__ __forceinline__ void gemm_f32(const float* __restrict__ xr,
                                         const __hip_bfloat16* wl,
                                         int l15, int kg, bool z, f32x4* acc)
{
    const short8 zed = {0,0,0,0,0,0,0,0};
    #pragma unroll
    for (int kc = 0; kc < NKC; ++kc) {
        short8 bf;
        if (z) bf = zed;
        else   bf = cvt8v(*(const f32x4*)(xr + kc * 32 + kg), *(const f32x4*)(xr + kc * 32 + kg + 4));
        #pragma unroll
        for (int g = 0; g < 3; ++g)
            #pragma unroll
            for (int jh = 0; jh < 2; ++jh) {
                short8 wf = *(const short8*)&wl[(g * 32 + jh * 16 + l15) * KP + kc * 32 + kg];
                acc[g * 2 + jh] = __builtin_amdgcn_mfma_f32_16x16x32_bf16(wf, bf, acc[g * 2 + jh], 0, 0, 0);
            }
    }
}

// 256 blocks x 512 threads. stage = bid>>6: 0=R0(gh0+fuse) 1=R1(gh1+fuse+out) 2=G1(gi1) 3=P0(gi0).
// Within stage: bt = (bid>>4)&3 (128 batch rows), jp = bid&15 (32 j-cols of all 3 gates).
// 8 waves: wave w owns rows rb + w*16 .. +16 (disjoint -> no redundant h reads).
// Dataflow sync: write-once per-(t,bt,jp) flags, depth-4 rings, no barriers.
__global__ __launch_bounds__(512) void gru_pipe(
    const float* __restrict__ x, const int* __restrict__ is_init,
    const float* __restrict__ h_in,
    const float* __restrict__ wih0, const float* __restrict__ whh0,
    const float* __restrict__ bih0, const float* __restrict__ bhh0,
    const float* __restrict__ wih1, const float* __restrict__ whh1,
    const float* __restrict__ bih1, const float* __restrict__ bhh1,
    char* __restrict__ ws, float* __restrict__ out)
{
    __shared__ __hip_bfloat16 wlds[96 * KP_];   // 99840 B

    __hip_bfloat16* h0r = (__hip_bfloat16*)ws;                 // [4][512][512]
    __hip_bfloat16* h1r = (__hip_bfloat16*)(ws + OFF_H1);
    __hip_bfloat16* gi0 = (__hip_bfloat16*)(ws + OFF_GI0);     // [4][4][16][128][96]
    __hip_bfloat16* gi1 = (__hip_bfloat16*)(ws + OFF_GI1);
    int* flg  = (int*)(ws + OFF_FLG);
    int* fh0  = flg;
    int* fh1  = flg + 8192;
    int* fgi0 = flg + 16384;
    int* fgi1 = flg + 24576;

    const int bid = blockIdx.x;
    const int stage = bid >> 6;
    const int bt = (bid >> 4) & 3;
    const int jp = bid & 15;
    const int rb = bt * 128;
    const int jb = jp * 32;
    const int tid = threadIdx.x;
    const int lane = tid & 63;
    const int w = tid >> 6;
    const int wid = w;
    const int l15 = lane & 15;
    const int q = lane >> 4;
    const int kg = q * 8;
    const int qr4 = q * 4;
    const int lr = w * 16 + l15;     // local row 0..127
    const int bw = rb + lr;          // global batch row

    // ---- stage weights into LDS (f32 -> bf16), once ----
    {
        const float* Wsrc; int K, KP;
        if (stage == 0)      { Wsrc = whh0; K = 512; KP = KP_; }
        else if (stage == 1) { Wsrc = whh1; K = 512; KP = KP_; }
        else if (stage == 2) { Wsrc = wih1; K = 512; KP = KP_; }
        else                 { Wsrc = wih0; K = 256; KP = KP0_; }
        const int nc8 = K / 8;
        for (int idx = tid; idx < 96 * nc8; idx += 512) {
            int gr = idx / nc8, c8 = idx - gr * nc8;
            int grow = (gr >> 5) * H_ + jb + (gr & 31);
            const float* p = Wsrc + (size_t)grow * K + c8 * 8;
            *(short8*)&wlds[gr * KP + c8 * 8] = cvt8v(*(const f32x4*)p, *(const f32x4*)(p + 4));
        }
    }

    // ---- per-lane constants for R stages ----
    f32x4 bR[2], bZ[2], bIN[2], bHN[2], hp[2];
    if (stage < 2) {
        const float* bi = stage ? bih1 : bih0;
        const float* bh = stage ? bhh1 : bhh0;
        #pragma unroll
        for (int jh = 0; jh < 2; ++jh) {
            const int j4 = jb + jh * 16 + qr4;
            bR[jh]  = *(const f32x4*)&bi[j4]          + *(const f32x4*)&bh[j4];
            bZ[jh]  = *(const f32x4*)&bi[H_ + j4]     + *(const f32x4*)&bh[H_ + j4];
            bIN[jh] = *(const f32x4*)&bi[2 * H_ + j4];
            bHN[jh] = *(const f32x4*)&bh[2 * H_ + j4];
            hp[jh]  = *(const f32x4*)&h_in[(size_t)bw * 2 * H_ + (size_t)stage * H_ + j4];
        }
    }
    __syncthreads();

    for (int t = 0; t < T_; ++t) {
        // ---- dataflow wait (wave 0 polls, others park at barrier) ----
        if (wid == 0) {
            const int* a = nullptr;
            if (stage == 0) {
                if (lane < 16 && t > 0)                        a = &fh0[((t - 1) * 4 + bt) * 16 + lane];
                else if (lane == 16)                           a = &fgi0[(t * 4 + bt) * 16 + jp];
                else if (lane >= 32 && lane < 48 && t >= 4)    a = &fgi1[((t - 4) * 4 + bt) * 16 + (lane - 32)];
            } else if (stage == 1) {
                if (lane < 16 && t > 0)                        a = &fh1[((t - 1) * 4 + bt) * 16 + lane];
                else if (lane == 16)                           a = &fgi1[(t * 4 + bt) * 16 + jp];
            } else if (stage == 2) {
                if (lane < 16)                                 a = &fh0[(t * 4 + bt) * 16 + lane];
                else if (lane == 16 && t >= 4)                 a = &fh1[((t - 4) * 4 + bt) * 16 + jp];
            } else {
                if (lane == 0 && t >= 4)                       a = &fh0[((t - 4) * 4 + bt) * 16 + jp];
            }
            if (a)
                while (__hip_atomic_load(a, __ATOMIC_RELAXED, __HIP_MEMORY_SCOPE_AGENT) == 0)
                    __builtin_amdgcn_s_sleep(1);
        }
        __syncthreads();

        f32x4 acc[6];
        #pragma unroll
        for (int jf = 0; jf < 6; ++jf) acc[jf] = f32x4{0.f, 0.f, 0.f, 0.f};

        if (stage < 2) {
            // ================= R0 / R1 =================
            const bool z = is_init[bw * T_ + t] != 0;
            // prefetch gi slab (latency hidden under GEMM)
            const __hip_bfloat16* slab = (stage ? gi1 : gi0)
                + ((((size_t)(t & 3) * 4 + bt) * 16 + jp) * 128 + lr) * 96;
            unsigned long long gu[6];
            #pragma unroll
            for (int jf = 0; jf < 6; ++jf)
                gu[jf] = load_sc8(slab + (jf >> 1) * 32 + (jf & 1) * 16 + qr4);

            __hip_bfloat16* ring = stage ? h1r : h0r;
            if (t == 0) {
                const float* hr = h_in + (size_t)bw * 2 * H_ + (size_t)stage * H_;
                gemm_f32<16, KP_>(hr, wlds, l15, kg, z, acc);
            } else {
                const __hip_bfloat16* hr = ring + (size_t)((t - 1) & 3) * HS + (size_t)bw * H_;
                gemm_bf<16, KP_>(hr, wlds, l15, kg, z, acc);
            }

            // fused gate epilogue
            __hip_bfloat16* hw = ring + (size_t)(t & 3) * HS + (size_t)bw * H_;
            #pragma unroll
            for (int jh = 0; jh < 2; ++jh) {
                const int j4 = jb + jh * 16 + qr4;
                const f32x4 giR = unpk(gu[jh]);
                const f32x4 giZ = unpk(gu[2 + jh]);
                const f32x4 giN = unpk(gu[4 + jh]);
                f32x4 hv;
                #pragma unroll
                for (int r = 0; r < 4; ++r) {
                    const float rr = sigm(giR[r] + acc[jh][r] + bR[jh][r]);
                    const float zz = sigm(giZ[r] + acc[2 + jh][r] + bZ[jh][r]);
                    const float nn = tanhf(giN[r] + bIN[jh][r] + rr * (acc[4 + jh][r] + bHN[jh][r]));
                    const float hprev = z ? 0.0f : hp[jh][r];
                    hv[r] = (1.0f - zz) * nn + zz * hprev;
                }
                hp[jh] = hv;
                store_h8(hw + j4, hv);
                if (stage == 1) {
                    *(f32x4*)&out[((size_t)bw * T_ + t) * H_ + j4] = hv;
                    if (t == T_ - 1)
                        *(f32x4*)&out[OUT_MAIN + (size_t)bw * 2 * H_ + H_ + j4] = hv;
                } else if (t == T_ - 1) {
                    *(f32x4*)&out[OUT_MAIN + (size_t)bw * 2 * H_ + j4] = hv;
                }
            }
            __syncthreads();   // all waves' sc-stores drained before publish
            if (tid == 0) {
                int* f = (stage ? fh1 : fh0) + (t * 4 + bt) * 16 + jp;
                __hip_atomic_store(f, 1, __ATOMIC_RELAXED, __HIP_MEMORY_SCOPE_AGENT);
            }
        } else if (stage == 2) {
            // ================= G1: gi1[t] = h0[t] @ Wih1^T =================
            const __hip_bfloat16* hr = h0r + (size_t)(t & 3) * HS + (size_t)bw * H_;
            gemm_bf<16, KP_>(hr, wlds, l15, kg, false, acc);
            __hip_bfloat16* slab = gi1 + ((((size_t)(t & 3) * 4 + bt) * 16 + jp) * 128 + lr) * 96;
            #pragma unroll
            for (int jf = 0; jf < 6; ++jf)
                store_h8(slab + (jf >> 1) * 32 + (jf & 1) * 16 + qr4, acc[jf]);
            __syncthreads();
            if (tid == 0)
                __hip_atomic_store(&fgi1[(t * 4 + bt) * 16 + jp], 1, __ATOMIC_RELAXED, __HIP_MEMORY_SCOPE_AGENT);
        } else {
            // ================= P0: gi0[t] = x[:,t,:] @ Wih0^T =================
            const float* xr = x + ((size_t)bw * T_ + t) * DIN_;
            gemm_f32<8, KP0_>(xr, wlds, l15, kg, false, acc);
            __hip_bfloat16* slab = gi0 + ((((size_t)(t & 3) * 4 + bt) * 16 + jp) * 128 + lr) * 96;
            #pragma unroll
            for (int jf = 0; jf < 6; ++jf)
                store_h8(slab + (jf >> 1) * 32 + (jf & 1) * 16 + qr4, acc[jf]);
            __syncthreads();
            if (tid == 0)
                __hip_atomic_store(&fgi0[(t * 4 + bt) * 16 + jp], 1, __ATOMIC_RELAXED, __HIP_MEMORY_SCOPE_AGENT);
        }
    }
}

extern "C" void kernel_launch(void* const* d_in, const int* in_sizes, int n_in,
                              void* d_out, int out_size, void* d_ws, size_t ws_size,
                              hipStream_t stream) {
    (void)in_sizes; (void)n_in; (void)out_size; (void)ws_size;
    const float* x    = (const float*)d_in[0];
    const int*   isin = (const int*)d_in[1];
    const float* h_in = (const float*)d_in[2];
    const float* wih0 = (const float*)d_in[3];
    const float* whh0 = (const float*)d_in[4];
    const float* bih0 = (const float*)d_in[5];
    const float* bhh0 = (const float*)d_in[6];
    const float* wih1 = (const float*)d_in[7];
    const float* whh1 = (const float*)d_in[8];
    const float* bih1 = (const float*)d_in[9];
    const float* bhh1 = (const float*)d_in[10];
    float* out = (float*)d_out;
    char* ws = (char*)d_ws;

    init_kernel<<<dim3(128), dim3(256), 0, stream>>>((int*)(ws + OFF_FLG));

    gru_pipe<<<dim3(256), dim3(512), 0, stream>>>(
        x, isin, h_in,
        wih0, whh0, bih0, bhh0,
        wih1, whh1, bih1, bhh1,
        ws, out);
}

// Round 8
// 1431.329 us; speedup vs baseline: 11.0629x; 1.0402x over previous
//
#include <hip/hip_runtime.h>
#include <hip/hip_bf16.h>

#define B_ 512
#define T_ 128
#define DIN_ 256
#define H_ 512
#define KP_ 520             // LDS weight row stride (bf16) for K=512 stages
#define KP0_ 264            // for K=256 stage (P0)
#define OUT_MAIN ((size_t)B_ * T_ * H_)

// ws byte offsets
#define OFF_H1  2097152ull
#define OFF_GI0 4194304ull
#define OFF_GI1 10485760ull
#define OFF_FLG 16777216ull

// transposed h ring: [slot4][b16=32][kc=16][512 elems], tile = 512 bf16 = 1024 B,
// within-tile elem offset = lane*8 (lane-major, exact MFMA B-frag order)
#define HTILE 512
#define HB16 8192            // elems per b16 group (16 tiles)
#define HSLOT (32 * HB16)    // elems per ring slot

// gi slab: [slot4][bt4][jp16][ jf6 ][ w8 ][ lane64 ][4 elems]  (contiguous 512B per (jf,w))
#define GISLAB 12288         // elems per (bt,jp)

typedef __attribute__((ext_vector_type(8))) short short8;
typedef __attribute__((ext_vector_type(4))) float f32x4;

__device__ __forceinline__ float sigm(float v) { return 1.0f / (1.0f + __expf(-v)); }

__device__ __forceinline__ unsigned short f2bf(float f) {
    union { __hip_bfloat16 b; unsigned short u; } c;
    c.b = __float2bfloat16(f);
    return c.u;
}

__device__ __forceinline__ short8 cvt8v(f32x4 u, f32x4 v) {
    short8 o;
    o[0] = (short)f2bf(u[0]); o[1] = (short)f2bf(u[1]);
    o[2] = (short)f2bf(u[2]); o[3] = (short)f2bf(u[3]);
    o[4] = (short)f2bf(v[0]); o[5] = (short)f2bf(v[1]);
    o[6] = (short)f2bf(v[2]); o[7] = (short)f2bf(v[3]);
    return o;
}

// coherent-point accesses (sc0 sc1): cross-XCD safe, no fences needed
__device__ __forceinline__ short8 load_h16(const __hip_bfloat16* p) {
    union { unsigned long long u[2]; short8 v; } r;
    r.u[0] = __hip_atomic_load((const unsigned long long*)p,       __ATOMIC_RELAXED, __HIP_MEMORY_SCOPE_AGENT);
    r.u[1] = __hip_atomic_load((const unsigned long long*)(p + 4), __ATOMIC_RELAXED, __HIP_MEMORY_SCOPE_AGENT);
    return r.v;
}

__device__ __forceinline__ unsigned long long load_sc8(const __hip_bfloat16* p) {
    return __hip_atomic_load((const unsigned long long*)p, __ATOMIC_RELAXED, __HIP_MEMORY_SCOPE_AGENT);
}

__device__ __forceinline__ void store_h8(__hip_bfloat16* p, f32x4 h4) {
    union { unsigned short s[4]; unsigned long long u; } r;
    r.s[0] = f2bf(h4[0]); r.s[1] = f2bf(h4[1]);
    r.s[2] = f2bf(h4[2]); r.s[3] = f2bf(h4[3]);
    __hip_atomic_store((unsigned long long*)p, r.u, __ATOMIC_RELAXED, __HIP_MEMORY_SCOPE_AGENT);
}

__device__ __forceinline__ f32x4 unpk(unsigned long long u) {
    f32x4 r;
    r[0] = __uint_as_float((unsigned)(u & 0xffffull) << 16);
    r[1] = __uint_as_float((unsigned)((u >> 16) & 0xffffull) << 16);
    r[2] = __uint_as_float((unsigned)((u >> 32) & 0xffffull) << 16);
    r[3] = __uint_as_float((unsigned)((u >> 48) & 0xffffull) << 16);
    return r;
}

__global__ void init_kernel(int* __restrict__ flg)
{
    int i = blockIdx.x * blockDim.x + threadIdx.x;
    if (i < 32768) flg[i] = 0;
}

// GEMM over transposed tiles: tb pre-offset by lane*8; per kc one contiguous 1024B wave read.
template<int NKC>
__device__ __forceinline__ void gemm_tile(const __hip_bfloat16* tb,
                                          const __hip_bfloat16* wl,
                                          int l15, int kg, bool z, f32x4* acc)
{
    const short8 zed = {0,0,0,0,0,0,0,0};
    #pragma unroll
    for (int kc = 0; kc < NKC; ++kc) {
        short8 bf = z ? zed : load_h16(tb + kc * HTILE);
        #pragma unroll
        for (int g = 0; g < 3; ++g)
            #pragma unroll
            for (int jh = 0; jh < 2; ++jh) {
                short8 wf = *(const short8*)&wl[(g * 32 + jh * 16 + l15) * KP_ + kc * 32 + kg];
                acc[g * 2 + jh] = __builtin_amdgcn_mfma_f32_16x16x32_bf16(wf, bf, acc[g * 2 + jh], 0, 0, 0);
            }
    }
}

// GEMM over f32 per-lane row pointers (x input, h_in at t=0)
template<int NKC, int KP>
__device__ __forceinline__ void gemm_f32(const float* __restrict__ xr,
                                         const __hip_bfloat16* wl,
                                         int l15, int kg, bool z, f32x4* acc)
{
    const short8 zed = {0,0,0,0,0,0,0,0};
    #pragma unroll
    for (int kc = 0; kc < NKC; ++kc) {
        short8 bf;
        if (z) bf = zed;
        else   bf = cvt8v(*(const f32x4*)(xr + kc * 32 + kg), *(const f32x4*)(xr + kc * 32 + kg + 4));
        #pragma unroll
        for (int g = 0; g < 3; ++g)
            #pragma unroll
            for (int jh = 0; jh < 2; ++jh) {
                short8 wf = *(const short8*)&wl[(g * 32 + jh * 16 + l15) * KP + kc * 32 + kg];
                acc[g * 2 + jh] = __builtin_amdgcn_mfma_f32_16x16x32_bf16(wf, bf, acc[g * 2 + jh], 0, 0, 0);
            }
    }
}

// 256 blocks x 512 threads. stage = bid>>6: 0=R0(gh0+fuse) 1=R1(gh1+fuse+out) 2=G1(gi1) 3=P0(gi0).
// bt = (bid>>4)&3 (128 batch rows), jp = bid&15 (32 j of all 3 gates). 8 waves = 8x16 rows.
// All exchanged data in lane-major transposed tiles -> fully coalesced sc traffic.
__global__ __launch_bounds__(512) void gru_pipe(
    const float* __restrict__ x, const int* __restrict__ is_init,
    const float* __restrict__ h_in,
    const float* __restrict__ wih0, const float* __restrict__ whh0,
    const float* __restrict__ bih0, const float* __restrict__ bhh0,
    const float* __restrict__ wih1, const float* __restrict__ whh1,
    const float* __restrict__ bih1, const float* __restrict__ bhh1,
    char* __restrict__ ws, float* __restrict__ out)
{
    __shared__ __hip_bfloat16 wlds[96 * KP_];   // 99840 B

    __hip_bfloat16* h0r = (__hip_bfloat16*)ws;                 // [4][32][16][512]
    __hip_bfloat16* h1r = (__hip_bfloat16*)(ws + OFF_H1);
    __hip_bfloat16* gi0 = (__hip_bfloat16*)(ws + OFF_GI0);     // [4][4][16][12288]
    __hip_bfloat16* gi1 = (__hip_bfloat16*)(ws + OFF_GI1);
    int* flg  = (int*)(ws + OFF_FLG);
    int* fh0  = flg;
    int* fh1  = flg + 8192;
    int* fgi0 = flg + 16384;
    int* fgi1 = flg + 24576;

    const int bid = blockIdx.x;
    const int stage = bid >> 6;
    const int bt = (bid >> 4) & 3;
    const int jp = bid & 15;
    const int rb = bt * 128;
    const int jb = jp * 32;
    const int tid = threadIdx.x;
    const int lane = tid & 63;
    const int w = tid >> 6;
    const int wid = w;
    const int l15 = lane & 15;
    const int q = lane >> 4;
    const int kg = q * 8;
    const int qr4 = q * 4;
    const int lr = w * 16 + l15;     // local row 0..127
    const int bw = rb + lr;          // global batch row
    const int b16 = bt * 8 + w;      // 16-row group index

    // ---- stage weights into LDS (f32 -> bf16), once ----
    {
        const float* Wsrc; int K, KP;
        if (stage == 0)      { Wsrc = whh0; K = 512; KP = KP_; }
        else if (stage == 1) { Wsrc = whh1; K = 512; KP = KP_; }
        else if (stage == 2) { Wsrc = wih1; K = 512; KP = KP_; }
        else                 { Wsrc = wih0; K = 256; KP = KP0_; }
        const int nc8 = K / 8;
        for (int idx = tid; idx < 96 * nc8; idx += 512) {
            int gr = idx / nc8, c8 = idx - gr * nc8;
            int grow = (gr >> 5) * H_ + jb + (gr & 31);
            const float* p = Wsrc + (size_t)grow * K + c8 * 8;
            *(short8*)&wlds[gr * KP + c8 * 8] = cvt8v(*(const f32x4*)p, *(const f32x4*)(p + 4));
        }
    }

    // ---- per-lane constants for R stages ----
    f32x4 bR[2], bZ[2], bIN[2], bHN[2], hp[2];
    if (stage < 2) {
        const float* bi = stage ? bih1 : bih0;
        const float* bh = stage ? bhh1 : bhh0;
        #pragma unroll
        for (int jh = 0; jh < 2; ++jh) {
            const int j4 = jb + jh * 16 + qr4;
            bR[jh]  = *(const f32x4*)&bi[j4]          + *(const f32x4*)&bh[j4];
            bZ[jh]  = *(const f32x4*)&bi[H_ + j4]     + *(const f32x4*)&bh[H_ + j4];
            bIN[jh] = *(const f32x4*)&bi[2 * H_ + j4];
            bHN[jh] = *(const f32x4*)&bh[2 * H_ + j4];
            hp[jh]  = *(const f32x4*)&h_in[(size_t)bw * 2 * H_ + (size_t)stage * H_ + j4];
        }
    }
    __syncthreads();

    for (int t = 0; t < T_; ++t) {
        // ---- dataflow wait (wave 0 polls, others park at barrier) ----
        if (wid == 0) {
            const int* a = nullptr;
            if (stage == 0) {
                if (lane < 16 && t > 0)                        a = &fh0[((t - 1) * 4 + bt) * 16 + lane];
                else if (lane == 16)                           a = &fgi0[(t * 4 + bt) * 16 + jp];
                else if (lane >= 32 && lane < 48 && t >= 4)    a = &fgi1[((t - 4) * 4 + bt) * 16 + (lane - 32)];
            } else if (stage == 1) {
                if (lane < 16 && t > 0)                        a = &fh1[((t - 1) * 4 + bt) * 16 + lane];
                else if (lane == 16)                           a = &fgi1[(t * 4 + bt) * 16 + jp];
            } else if (stage == 2) {
                if (lane < 16)                                 a = &fh0[(t * 4 + bt) * 16 + lane];
                else if (lane == 16 && t >= 4)                 a = &fh1[((t - 4) * 4 + bt) * 16 + jp];
            } else {
                if (lane == 0 && t >= 4)                       a = &fh0[((t - 4) * 4 + bt) * 16 + jp];
            }
            if (a)
                while (__hip_atomic_load(a, __ATOMIC_RELAXED, __HIP_MEMORY_SCOPE_AGENT) == 0)
                    __builtin_amdgcn_s_sleep(1);
        }
        __syncthreads();

        f32x4 acc[6];
        #pragma unroll
        for (int jf = 0; jf < 6; ++jf) acc[jf] = f32x4{0.f, 0.f, 0.f, 0.f};

        if (stage < 2) {
            // ================= R0 / R1 =================
            const bool z = is_init[bw * T_ + t] != 0;
            // prefetch gi slab (lane-major contiguous)
            const __hip_bfloat16* slab = (stage ? gi1 : gi0)
                + (((size_t)(t & 3) * 4 + bt) * 16 + jp) * GISLAB;
            unsigned long long gu[6];
            #pragma unroll
            for (int jf = 0; jf < 6; ++jf)
                gu[jf] = load_sc8(slab + ((jf * 8 + w) * 64 + lane) * 4);

            __hip_bfloat16* ring = stage ? h1r : h0r;
            if (t == 0) {
                const float* hr = h_in + (size_t)bw * 2 * H_ + (size_t)stage * H_;
                gemm_f32<16, KP_>(hr, wlds, l15, kg, z, acc);
            } else {
                const __hip_bfloat16* tb = ring + ((size_t)((t - 1) & 3) * 32 + b16) * HB16 + (size_t)lane * 8;
                gemm_tile<16>(tb, wlds, l15, kg, z, acc);
            }

            // fused gate epilogue; h store into transposed tile (kc = jp)
            __hip_bfloat16* hw = ring + ((size_t)(t & 3) * 32 + b16) * HB16 + (size_t)jp * HTILE;
            #pragma unroll
            for (int jh = 0; jh < 2; ++jh) {
                const int j4 = jb + jh * 16 + qr4;
                const f32x4 giR = unpk(gu[jh]);
                const f32x4 giZ = unpk(gu[2 + jh]);
                const f32x4 giN = unpk(gu[4 + jh]);
                f32x4 hv;
                #pragma unroll
                for (int r = 0; r < 4; ++r) {
                    const float rr = sigm(giR[r] + acc[jh][r] + bR[jh][r]);
                    const float zz = sigm(giZ[r] + acc[2 + jh][r] + bZ[jh][r]);
                    const float nn = tanhf(giN[r] + bIN[jh][r] + rr * (acc[4 + jh][r] + bHN[jh][r]));
                    const float hprev = z ? 0.0f : hp[jh][r];
                    hv[r] = (1.0f - zz) * nn + zz * hprev;
                }
                hp[jh] = hv;
                const int qp = jh * 2 + (q >> 1);
                store_h8(hw + (qp * 16 + l15) * 8 + (q & 1) * 4, hv);
                if (stage == 1) {
                    *(f32x4*)&out[((size_t)bw * T_ + t) * H_ + j4] = hv;
                    if (t == T_ - 1)
                        *(f32x4*)&out[OUT_MAIN + (size_t)bw * 2 * H_ + H_ + j4] = hv;
                } else if (t == T_ - 1) {
                    *(f32x4*)&out[OUT_MAIN + (size_t)bw * 2 * H_ + j4] = hv;
                }
            }
            __syncthreads();   // all waves' sc-stores drained before publish
            if (tid == 0) {
                int* f = (stage ? fh1 : fh0) + (t * 4 + bt) * 16 + jp;
                __hip_atomic_store(f, 1, __ATOMIC_RELAXED, __HIP_MEMORY_SCOPE_AGENT);
            }
        } else if (stage == 2) {
            // ================= G1: gi1[t] = h0[t] @ Wih1^T =================
            const __hip_bfloat16* tb = h0r + ((size_t)(t & 3) * 32 + b16) * HB16 + (size_t)lane * 8;
            gemm_tile<16>(tb, wlds, l15, kg, false, acc);
            __hip_bfloat16* slab = gi1 + (((size_t)(t & 3) * 4 + bt) * 16 + jp) * GISLAB;
            #pragma unroll
            for (int jf = 0; jf < 6; ++jf)
                store_h8(slab + ((jf * 8 + w) * 64 + lane) * 4, acc[jf]);
            __syncthreads();
            if (tid == 0)
                __hip_atomic_store(&fgi1[(t * 4 + bt) * 16 + jp], 1, __ATOMIC_RELAXED, __HIP_MEMORY_SCOPE_AGENT);
        } else {
            // ================= P0: gi0[t] = x[:,t,:] @ Wih0^T =================
            const float* xr = x + ((size_t)bw * T_ + t) * DIN_;
            gemm_f32<8, KP0_>(xr, wlds, l15, kg, false, acc);
            __hip_bfloat16* slab = gi0 + (((size_t)(t & 3) * 4 + bt) * 16 + jp) * GISLAB;
            #pragma unroll
            for (int jf = 0; jf < 6; ++jf)
                store_h8(slab + ((jf * 8 + w) * 64 + lane) * 4, acc[jf]);
            __syncthreads();
            if (tid == 0)
                __hip_atomic_store(&fgi0[(t * 4 + bt) * 16 + jp], 1, __ATOMIC_RELAXED, __HIP_MEMORY_SCOPE_AGENT);
        }
    }
}

extern "C" void kernel_launch(void* const* d_in, const int* in_sizes, int n_in,
                              void* d_out, int out_size, void* d_ws, size_t ws_size,
                              hipStream_t stream) {
    (void)in_sizes; (void)n_in; (void)out_size; (void)ws_size;
    const float* x    = (const float*)d_in[0];
    const int*   isin = (const int*)d_in[1];
    const float* h_in = (const float*)d_in[2];
    const float* wih0 = (const float*)d_in[3];
    const float* whh0 = (const float*)d_in[4];
    const float* bih0 = (const float*)d_in[5];
    const float* bhh0 = (const float*)d_in[6];
    const float* wih1 = (const float*)d_in[7];
    const float* whh1 = (const float*)d_in[8];
    const float* bih1 = (const float*)d_in[9];
    const float* bhh1 = (const float*)d_in[10];
    float* out = (float*)d_out;
    char* ws = (char*)d_ws;

    init_kernel<<<dim3(128), dim3(256), 0, stream>>>((int*)(ws + OFF_FLG));

    gru_pipe<<<dim3(256), dim3(512), 0, stream>>>(
        x, isin, h_in,
        wih0, whh0, bih0, bhh0,
        wih1, whh1, bih1, bhh1,
        ws, out);
}